// Round 9
// baseline (46.160 us; speedup 1.0000x reference)
//
#include <hip/hip_runtime.h>

#define DIM     400
#define B       32
#define NCAND   14505
#define NROUND  3627      // ceil(NCAND/4)
#define TSTRIPS 256
#define THREADS 256

// wave = 4 candidate-slots x 16 dim-lanes; lane u owns f4-chunks u+16k (k=0..5)
// plus tail chunk 96+u for u<4 (400 dims = 6x64 + 16).
// q/o register-resident (~56 VGPR), candidate row streamed as 7 dwordx4 loads.
// Single buffer (no ping-pong -> no spill motive); 4 waves/SIMD hide L2 latency.
__global__ __launch_bounds__(THREADS, 2)
void score_kernel(const float* __restrict__ ent,
                  const float* __restrict__ relc,
                  const float* __restrict__ relo,
                  const float* __restrict__ onev,
                  const int*   __restrict__ pairs,
                  const int*   __restrict__ cidx,
                  float* __restrict__ out) {
    const int fid  = blockIdx.x;
    const int xcd  = fid & 7;            // same strip residue -> same XCD L2
    const int rest = fid >> 3;
    const int bq   = rest & 7;           // batch quad
    const int tc   = rest >> 3;          // 0..31
    const int t    = xcd + 8 * tc;       // strip 0..255

    const int tid  = threadIdx.x;
    const int lane = tid & 63;
    const int u    = lane & 15;          // dim-lane
    const int g    = lane >> 4;          // candidate slot 0..3
    const int b    = __builtin_amdgcn_readfirstlane(bq * 4 + (tid >> 6));

    const int hd = pairs[b * 2 + 0];
    const int rl = pairs[b * 2 + 1];
    const float4* hb = (const float4*)(ent  + (size_t)hd * DIM) + u;
    const float4* cb = (const float4*)(relc + (size_t)rl * DIM) + u;
    const float4* ob = (const float4*)(relo + (size_t)rl * DIM) + u;

    // ---- one-time: q,o into registers; base = one + 0.98*sum(o) ----
    float4 q[7], o[7];
    float oa = 0.f;
#pragma unroll
    for (int k = 0; k < 6; ++k) {
        float4 h = hb[16 * k], c = cb[16 * k];
        q[k] = make_float4(h.x + c.x, h.y + c.y, h.z + c.z, h.w + c.w);
        o[k] = ob[16 * k];
        oa += o[k].x + o[k].y + o[k].z + o[k].w;
    }
    if (u < 4) {
        float4 h = hb[96], c = cb[96];
        q[6] = make_float4(h.x + c.x, h.y + c.y, h.z + c.z, h.w + c.w);
        o[6] = ob[96];
        oa += o[6].x + o[6].y + o[6].z + o[6].w;
    }
    oa += __shfl_xor(oa, 1);
    oa += __shfl_xor(oa, 2);
    oa += __shfl_xor(oa, 4);
    oa += __shfl_xor(oa, 8);             // sum over 16 dim-lanes = full 400-dim sum
    const float base = onev[0] + 0.98f * oa;

    const float4* entu = (const float4*)ent + u;   // row ptr = entu + ci*100

    for (int rr = t; rr < NROUND; rr += TSTRIPS) {
        const int cand = 4 * rr + g;
        const int ci   = cidx[cand < NCAND ? cand : NCAND - 1];   // clamp: harmless dup
        const float4* p = entu + (size_t)ci * 100;

        // contiguous load block: compiler issues all 7 dwordx4 before compute
        float4 cbuf[7];
#pragma unroll
        for (int k = 0; k < 6; ++k) cbuf[k] = p[16 * k];
        if (u < 4) cbuf[6] = p[96];

        float am0 = 0.f, ad0 = 0.f, am1 = 0.f, ad1 = 0.f;   // 2 independent chains
#define E(vc, vq, vo, AM, AD)                     \
        {                                         \
            float d_ = (vc) - (vq);               \
            AM += fmaxf(fabsf(d_), (vo));         \
            AD += fabsf(d_);                      \
        }
#define F4(k, AM, AD)                             \
        E(cbuf[k].x, q[k].x, o[k].x, AM, AD)      \
        E(cbuf[k].y, q[k].y, o[k].y, AM, AD)      \
        E(cbuf[k].z, q[k].z, o[k].z, AM, AD)      \
        E(cbuf[k].w, q[k].w, o[k].w, AM, AD)

        F4(0, am0, ad0) F4(1, am1, ad1)
        F4(2, am0, ad0) F4(3, am1, ad1)
        F4(4, am0, ad0) F4(5, am1, ad1)
        if (u < 4) { F4(6, am0, ad0) }
#undef F4
#undef E

        float s_ = fmaf(-0.98f, am0 + am1, -0.02f * (ad0 + ad1));
        s_ += __shfl_xor(s_, 1);
        s_ += __shfl_xor(s_, 2);
        s_ += __shfl_xor(s_, 4);
        s_ += __shfl_xor(s_, 8);

        if (u == 0 && cand < NCAND)
            out[(size_t)b * NCAND + cand] = base + s_;   // lanes 0/16/32/48 -> 16B segment
    }
}

extern "C" void kernel_launch(void* const* d_in, const int* in_sizes, int n_in,
                              void* d_out, int out_size, void* d_ws, size_t ws_size,
                              hipStream_t stream) {
    const float* ent   = (const float*)d_in[0];
    const float* relc  = (const float*)d_in[1];
    const float* relo  = (const float*)d_in[2];
    const float* onev  = (const float*)d_in[3];
    const int*   pairs = (const int*)d_in[4];
    const int*   cidx  = (const int*)d_in[5];
    float*       out   = (float*)d_out;

    const int grid = 8 * 8 * 32;   // 2048 = xcd(8) * bquad(8) * strip-chunk(32)
    score_kernel<<<grid, THREADS, 0, stream>>>(ent, relc, relo, onev, pairs, cidx, out);
}